// Round 3
// baseline (354.317 us; speedup 1.0000x reference)
//
#include <hip/hip_runtime.h>

// MultiHeadHPLSTM — fp32 I/O (per reference dtypes), bf16 MFMA internal.
//   prep: transpose weights fp32->bf16
//   GEMM1: X(bf16) = inputs(f32) @ W_in + b_in            (32768x512, K=512)
//   gates_scan<0>: per-64-row-chunk gate GEMM (recomputed) + local scan -> Agg,Bgg
//   scan_super / scan_top: two-level 64x64 affine prefix combine
//   gates_scan<1>: recompute gates, apply scan, p=og*c, p@W_c+b_c -> O (bf16, over X)
//   GEMM4: out(f32) = O @ W_out + b_out                   (32768x512, K=512)
// ws peak ~35.1 MB.

typedef unsigned short ushort;
typedef __bf16 bf16x8 __attribute__((ext_vector_type(8)));
typedef float f32x4 __attribute__((ext_vector_type(4)));

#define CROWS 64     // rows per chunk
#define NCH  4096    // chunks (262144 / 64)
#define NSUP 64      // superchunks of 64 chunks

#define GLOAD16(gp, lp) __builtin_amdgcn_global_load_lds( \
    (const __attribute__((address_space(1))) void*)(gp),  \
    (__attribute__((address_space(3))) void*)(lp), 16, 0, 0)

__device__ inline float b2f(ushort u) {
    return __builtin_bit_cast(float, (unsigned)u << 16);
}
__device__ inline ushort f2b(float f) {
    unsigned x = __builtin_bit_cast(unsigned, f);
    x += 0x7FFFu + ((x >> 16) & 1u);   // RNE
    return (ushort)(x >> 16);
}

// ---------------- weight prep (fp32 -> transposed bf16) ----------------
__global__ void transpose512(const float* __restrict__ src, ushort* __restrict__ dst) {
    __shared__ float tile[32][33];
    const int tx = threadIdx.x & 31, ty = threadIdx.x >> 5;   // 32 x 8
    const int x0 = blockIdx.x * 32, y0 = blockIdx.y * 32;
    #pragma unroll
    for (int dy = 0; dy < 32; dy += 8)
        tile[ty + dy][tx] = src[(size_t)(y0 + ty + dy) * 512 + x0 + tx];
    __syncthreads();
    #pragma unroll
    for (int dy = 0; dy < 32; dy += 8)
        dst[(size_t)(x0 + ty + dy) * 512 + y0 + tx] = f2b(tile[tx][ty + dy]);
}

__global__ void prep_small(const float* __restrict__ W_gates, const float* __restrict__ W_og,
                           const float* __restrict__ W_c,
                           const float* __restrict__ b_gates, const float* __restrict__ b_og,
                           ushort* __restrict__ W2T, ushort* __restrict__ WcT, float* __restrict__ b2) {
    const int idx = blockIdx.x * 256 + threadIdx.x;
    if (idx < 16384) {                       // W2T[n][k]: n<192 from W_gates, else W_og
        const int n = idx >> 6, k = idx & 63;
        W2T[idx] = f2b((n < 192) ? W_gates[k * 192 + n] : W_og[(k << 6) + (n - 192)]);
    } else if (idx < 16384 + 4096) {         // WcT[n][k]
        const int i = idx - 16384;
        const int n = i >> 6, k = i & 63;
        WcT[i] = f2b(W_c[(k << 6) + n]);
    } else if (idx < 16384 + 4096 + 256) {   // fused bias [b_gates | b_og] (fp32)
        const int i = idx - 20480;
        b2[i] = (i < 192) ? b_gates[i] : b_og[i - 192];
    }
}

// ---------------- big GEMM: C = A(MxK) * Bt(NxK)^T + bias ----------------
// A32: A is fp32 (convert while staging); else bf16 via global_load_lds.
// C32: write fp32; else bf16.
template <int BM, int BN, int WAVES_M, int WAVES_N, int A32, int C32>
__global__ __launch_bounds__(256)
void gemm_bt(const void* __restrict__ Av, const ushort* __restrict__ Bt,
             const float* __restrict__ bias, void* __restrict__ Cv,
             int M, int N, int K) {
    constexpr int WM = BM / WAVES_M, WN = BN / WAVES_N;
    constexpr int MT = WM / 16, NT = WN / 16;
    __shared__ __align__(16) ushort sA[BM * 32];
    __shared__ __align__(16) ushort sB[BN * 32];

    const int t = threadIdx.x, w = t >> 6, lane = t & 63;
    const int wm = (w / WAVES_N) * WM, wn = (w % WAVES_N) * WN;
    const long bm = (long)blockIdx.x * BM, bn = (long)blockIdx.y * BN;

    f32x4 acc[MT][NT] = {};

    for (int k0 = 0; k0 < K; k0 += 32) {
        if (A32) {
            const float* A = (const float*)Av;
            #pragma unroll
            for (int is = 0; is < BM / 32; ++is) {
                const int row = is * 32 + (t >> 3), col = (t & 7) * 4;
                const float4 v = *(const float4*)(A + (bm + row) * (long)K + k0 + col);
                *(ushort4*)&sA[row * 32 + col] =
                    make_ushort4(f2b(v.x), f2b(v.y), f2b(v.z), f2b(v.w));
            }
        } else {
            const ushort* A = (const ushort*)Av;
            #pragma unroll
            for (int is = 0; is < BM / 64; ++is)
                GLOAD16(A + (bm + is * 64 + (t >> 2)) * (long)K + k0 + (t & 3) * 8,
                        (char*)sA + is * 4096 + w * 1024);
        }
        #pragma unroll
        for (int is = 0; is < BN / 64; ++is)
            GLOAD16(Bt + (bn + is * 64 + (t >> 2)) * (long)K + k0 + (t & 3) * 8,
                    (char*)sB + is * 4096 + w * 1024);
        __syncthreads();

        bf16x8 af[MT], bfr[NT];
        #pragma unroll
        for (int i = 0; i < MT; ++i)
            af[i] = *(const bf16x8*)&sA[(wm + i * 16 + (lane & 15)) * 32 + (lane >> 4) * 8];
        #pragma unroll
        for (int j = 0; j < NT; ++j)
            bfr[j] = *(const bf16x8*)&sB[(wn + j * 16 + (lane & 15)) * 32 + (lane >> 4) * 8];
        #pragma unroll
        for (int i = 0; i < MT; ++i)
            #pragma unroll
            for (int j = 0; j < NT; ++j)
                acc[i][j] = __builtin_amdgcn_mfma_f32_16x16x32_bf16(af[i], bfr[j], acc[i][j], 0, 0, 0);
        __syncthreads();
    }

    // epilogue: C/D layout col = lane&15, row = (lane>>4)*4 + r   [verified m89/m91]
    #pragma unroll
    for (int i = 0; i < MT; ++i)
        #pragma unroll
        for (int j = 0; j < NT; ++j) {
            const long col = bn + wn + j * 16 + (lane & 15);
            const float bv = bias[col];
            #pragma unroll
            for (int r = 0; r < 4; ++r) {
                const long row = bm + wm + i * 16 + ((lane >> 4) << 2) + r;
                const float v = acc[i][j][r] + bv;
                if (C32) ((float*)Cv)[row * (long)N + col] = v;
                else     ((ushort*)Cv)[row * (long)N + col] = f2b(v);
            }
        }
}

// ---------------- fused gate GEMM + scan ----------------
// One block = one 64-row chunk of X (bf16). Gates recomputed both passes, never in HBM.
// LDS phases alias: phase1 staging (sA 8K | sB 32K), phase2 gates (sG 36.9K | sP 9.2K).
template <int APPLY>
__global__ __launch_bounds__(256)
void gates_scan(const ushort* __restrict__ X, const ushort* __restrict__ W2T,
                const float* __restrict__ b2, const ushort* __restrict__ WcT,
                const float* __restrict__ b_c,
                float* __restrict__ Agg, float* __restrict__ Bgg,
                const float* __restrict__ PreS, ushort* __restrict__ O) {
    __shared__ __align__(16) char smem[46080];
    ushort* sA = (ushort*)smem;             // phase1: X chunk 64x64
    ushort* sB = (ushort*)(smem + 8192);    // phase1: W2T 256x64
    ushort* sG = (ushort*)smem;             // phase2: 4 gate arrays [64*72] bf16
    ushort* sP = (ushort*)(smem + 36864);   // phase2: p 64x72 bf16
    __shared__ __align__(16) ushort sWc[64 * 64];

    const int t = threadIdx.x, w = t >> 6, lane = t & 63;
    const int blk = blockIdx.x;
    const long row0 = (long)blk * CROWS;

    #pragma unroll
    for (int is = 0; is < 2; ++is)
        GLOAD16(X + (row0 + is * 32 + (t >> 3)) * 64 + (t & 7) * 8,
                (char*)sA + is * 4096 + w * 1024);
    #pragma unroll
    for (int is = 0; is < 8; ++is)
        GLOAD16(W2T + (is * 32 + (t >> 3)) * 64 + (t & 7) * 8,
                (char*)sB + is * 4096 + w * 1024);
    if (APPLY) {
        #pragma unroll
        for (int is = 0; is < 2; ++is)
            GLOAD16(WcT + (is * 32 + (t >> 3)) * 64 + (t & 7) * 8,
                    (char*)sWc + is * 4096 + w * 1024);
    }
    __syncthreads();

    // gate GEMM: 64x256 tile, K=64; waves 2x2 -> 32x128 per wave
    const int wm = (w >> 1) * 32, wn = (w & 1) * 128;
    f32x4 acc[2][8] = {};
    #pragma unroll
    for (int kk = 0; kk < 2; ++kk) {
        bf16x8 af[2], bfr[8];
        #pragma unroll
        for (int i = 0; i < 2; ++i)
            af[i] = *(const bf16x8*)&sA[(wm + i * 16 + (lane & 15)) * 64 + kk * 32 + (lane >> 4) * 8];
        #pragma unroll
        for (int j = 0; j < 8; ++j)
            bfr[j] = *(const bf16x8*)&sB[(wn + j * 16 + (lane & 15)) * 64 + kk * 32 + (lane >> 4) * 8];
        #pragma unroll
        for (int i = 0; i < 2; ++i)
            #pragma unroll
            for (int j = 0; j < 8; ++j)
                acc[i][j] = __builtin_amdgcn_mfma_f32_16x16x32_bf16(af[i], bfr[j], acc[i][j], 0, 0, 0);
    }
    __syncthreads();   // all LDS reads done before sG overwrites sA/sB

    // bias + activation -> sG (bf16): g0=fg g1=ig g2=h g3=og
    #pragma unroll
    for (int j = 0; j < 8; ++j) {
        const int col = wn + j * 16 + (lane & 15);
        const float bv = b2[col];
        const int g = col >> 6, ch = col & 63;
        #pragma unroll
        for (int i = 0; i < 2; ++i)
            #pragma unroll
            for (int r = 0; r < 4; ++r) {
                const int row = wm + i * 16 + ((lane >> 4) << 2) + r;
                float v = acc[i][j][r] + bv;
                v = (g == 2) ? tanhf(v) : 1.0f / (1.0f + __expf(-v));
                sG[g * 4608 + row * 72 + ch] = f2b(v);
            }
    }
    __syncthreads();

    if (!APPLY) {
        if (t < 64) {   // thread = channel
            float a = 1.0f, b = 0.0f;
            #pragma unroll 8
            for (int r = 0; r < CROWS; ++r) {
                const float fg = b2f(sG[r * 72 + t]);
                const float hr = b2f(sG[4608 + r * 72 + t]) * b2f(sG[9216 + r * 72 + t]);
                a *= fg;
                b = fmaf(b, fg, hr);
            }
            Agg[blk * 64 + t] = a;
            Bgg[blk * 64 + t] = b;
        }
        return;
    }

    // APPLY: chunk-start state c0 = A_pre * c_super + B_pre
    if (t < 64) {
        const int s = blk >> 6;
        float c = fmaf(PreS[s * 64 + t], Agg[blk * 64 + t], Bgg[blk * 64 + t]);
        #pragma unroll 8
        for (int r = 0; r < CROWS; ++r) {
            const float fg = b2f(sG[r * 72 + t]);
            const float hr = b2f(sG[4608 + r * 72 + t]) * b2f(sG[9216 + r * 72 + t]);
            c = fmaf(c, fg, hr);
            sP[r * 72 + t] = f2b(b2f(sG[13824 + r * 72 + t]) * c);   // p = og * c
        }
    }
    __syncthreads();

    // O_tile = p(64x64) @ WcT^T + b_c  (bf16 out, in-place over X chunk)
    const int wm2 = (w >> 1) * 32, wn2 = (w & 1) * 32;
    f32x4 acc2[2][2] = {};
    #pragma unroll
    for (int kk = 0; kk < 2; ++kk) {
        bf16x8 pa[2], wb[2];
        #pragma unroll
        for (int i = 0; i < 2; ++i)
            pa[i] = *(const bf16x8*)&sP[(wm2 + i * 16 + (lane & 15)) * 72 + kk * 32 + (lane >> 4) * 8];
        #pragma unroll
        for (int j = 0; j < 2; ++j)
            wb[j] = *(const bf16x8*)&sWc[(wn2 + j * 16 + (lane & 15)) * 64 + kk * 32 + (lane >> 4) * 8];
        #pragma unroll
        for (int i = 0; i < 2; ++i)
            #pragma unroll
            for (int j = 0; j < 2; ++j)
                acc2[i][j] = __builtin_amdgcn_mfma_f32_16x16x32_bf16(pa[i], wb[j], acc2[i][j], 0, 0, 0);
    }
    #pragma unroll
    for (int i = 0; i < 2; ++i)
        #pragma unroll
        for (int j = 0; j < 2; ++j) {
            const int col = wn2 + j * 16 + (lane & 15);
            const float bv = b_c[col];
            #pragma unroll
            for (int r = 0; r < 4; ++r) {
                const int row = wm2 + i * 16 + ((lane >> 4) << 2) + r;
                O[(row0 + row) * 64 + col] = f2b(acc2[i][j][r] + bv);
            }
        }
}

// ---------------- two-level prefix combine ----------------
__global__ void scan_super(float* __restrict__ Agg, float* __restrict__ Bgg,
                           float* __restrict__ SA, float* __restrict__ SB) {
    const int s = blockIdx.x, ch = threadIdx.x;   // 64 blocks x 64 threads
    float a = 1.0f, b = 0.0f;
    for (int j = 0; j < 64; ++j) {
        const int idx = (s * 64 + j) * 64 + ch;
        const float a2 = Agg[idx], bb = Bgg[idx];
        Agg[idx] = a;            // exclusive intra-super prefix, in place
        Bgg[idx] = b;
        a *= a2;
        b = fmaf(b, a2, bb);
    }
    SA[s * 64 + ch] = a;
    SB[s * 64 + ch] = b;
}

__global__ void scan_top(const float* __restrict__ SA, const float* __restrict__ SB,
                         float* __restrict__ PreS) {
    const int ch = threadIdx.x;   // 1 block, 64 threads
    float c = 0.0f;
    for (int s = 0; s < 64; ++s) {
        PreS[s * 64 + ch] = c;    // exclusive: state at super start
        c = fmaf(c, SA[s * 64 + ch], SB[s * 64 + ch]);
    }
}

// ---------------- launch ----------------
extern "C" void kernel_launch(void* const* d_in, const int* in_sizes, int n_in,
                              void* d_out, int out_size, void* d_ws, size_t ws_size,
                              hipStream_t stream) {
    const float* inputs  = (const float*)d_in[0];
    const float* W_in    = (const float*)d_in[1];
    const float* b_in    = (const float*)d_in[2];
    const float* W_gates = (const float*)d_in[3];
    const float* b_gates = (const float*)d_in[4];
    const float* W_og    = (const float*)d_in[5];
    const float* b_og    = (const float*)d_in[6];
    const float* W_c     = (const float*)d_in[7];
    const float* b_c     = (const float*)d_in[8];
    const float* W_out   = (const float*)d_in[9];
    const float* b_out   = (const float*)d_in[10];
    float* out = (float*)d_out;

    char* ws = (char*)d_ws;                          // peak use ~35.1 MB
    ushort* X     = (ushort*)(ws);                   // 33554432 B (O in-place)
    ushort* WinT  = (ushort*)(ws + 33554432);        // 524288
    ushort* WoutT = (ushort*)(ws + 34078720);        // 524288
    ushort* W2T   = (ushort*)(ws + 34603008);        // 32768
    ushort* WcT   = (ushort*)(ws + 34635776);        // 8192
    float*  b2    = (float*)(ws + 34643968);         // 1024
    float*  Agg   = (float*)(ws + 34644992);         // 1048576
    float*  Bgg   = (float*)(ws + 35693568);         // 1048576
    float*  SA    = (float*)(ws + 36742144);         // 16384
    float*  SB    = (float*)(ws + 36758528);         // 16384
    float*  PreS  = (float*)(ws + 36774912);         // 16384
    ushort* O = X;

    transpose512<<<dim3(16, 16), 256, 0, stream>>>(W_in, WinT);
    transpose512<<<dim3(16, 16), 256, 0, stream>>>(W_out, WoutT);
    prep_small<<<81, 256, 0, stream>>>(W_gates, W_og, W_c, b_gates, b_og, W2T, WcT, b2);

    gemm_bt<128, 128, 2, 2, 1, 0><<<dim3(256, 4), 256, 0, stream>>>(
        inputs, WinT, b_in, X, 32768, 512, 512);

    gates_scan<0><<<NCH, 256, 0, stream>>>(X, W2T, b2, WcT, b_c, Agg, Bgg, PreS, O);
    scan_super<<<NSUP, 64, 0, stream>>>(Agg, Bgg, SA, SB);
    scan_top<<<1, 64, 0, stream>>>(SA, SB, PreS);
    gates_scan<1><<<NCH, 256, 0, stream>>>(X, W2T, b2, WcT, b_c, Agg, Bgg, PreS, O);

    gemm_bt<128, 128, 2, 2, 0, 1><<<dim3(256, 4), 256, 0, stream>>>(
        O, WoutT, b_out, out, 32768, 512, 512);
}

// Round 4
// 324.617 us; speedup vs baseline: 1.0915x; 1.0915x over previous
//
#include <hip/hip_runtime.h>

// MultiHeadHPLSTM — fp32 I/O, bf16 MFMA internal.
// R3 -> R4: XOR-swizzled LDS tiles (kill 16-way bank conflicts), packed gate
// weights [ig|h|fg|og] (in-register hr=sig*tanh, 2 scan arrays not 3),
// gates_scan LDS 62->48 KB (3 blocks/CU), swizzle in big GEMMs too.

typedef unsigned short ushort;
typedef __bf16 bf16x8 __attribute__((ext_vector_type(8)));
typedef float f32x4 __attribute__((ext_vector_type(4)));

#define CROWS 64
#define NCH  4096
#define NSUP 64

#define GLOAD16(gp, lp) __builtin_amdgcn_global_load_lds( \
    (const __attribute__((address_space(1))) void*)(gp),  \
    (__attribute__((address_space(3))) void*)(lp), 16, 0, 0)

__device__ inline float b2f(ushort u) {
    return __builtin_bit_cast(float, (unsigned)u << 16);
}
__device__ inline ushort f2b(float f) {
    unsigned x = __builtin_bit_cast(unsigned, f);
    x += 0x7FFFu + ((x >> 16) & 1u);   // RNE
    return (ushort)(x >> 16);
}
__device__ inline float sigm(float v) { return 1.0f / (1.0f + __expf(-v)); }
__device__ inline float tanh_fast(float v) { return 2.0f / (1.0f + __expf(-2.0f * v)) - 1.0f; }

// ---------------- weight prep (fp32 -> transposed bf16) ----------------
__global__ void transpose512(const float* __restrict__ src, ushort* __restrict__ dst) {
    __shared__ float tile[32][33];
    const int tx = threadIdx.x & 31, ty = threadIdx.x >> 5;
    const int x0 = blockIdx.x * 32, y0 = blockIdx.y * 32;
    #pragma unroll
    for (int dy = 0; dy < 32; dy += 8)
        tile[ty + dy][tx] = src[(size_t)(y0 + ty + dy) * 512 + x0 + tx];
    __syncthreads();
    #pragma unroll
    for (int dy = 0; dy < 32; dy += 8)
        dst[(size_t)(x0 + ty + dy) * 512 + y0 + tx] = f2b(tile[tx][ty + dy]);
}

// W2T packed col order: [ig(0..63) | h(64..127) | fg(128..191) | og(192..255)]
__global__ void prep_small(const float* __restrict__ W_gates, const float* __restrict__ W_og,
                           const float* __restrict__ W_c,
                           const float* __restrict__ b_gates, const float* __restrict__ b_og,
                           ushort* __restrict__ W2T, ushort* __restrict__ WcT, float* __restrict__ b2) {
    const int idx = blockIdx.x * 256 + threadIdx.x;
    if (idx < 16384) {
        const int n = idx >> 6, k = idx & 63;
        float v;
        if      (n < 64)  v = W_gates[k * 192 + 64 + n];          // ig
        else if (n < 128) v = W_gates[k * 192 + 128 + (n - 64)];  // h
        else if (n < 192) v = W_gates[k * 192 + (n - 128)];       // fg
        else              v = W_og[k * 64 + (n - 192)];           // og
        W2T[idx] = f2b(v);
    } else if (idx < 16384 + 4096) {
        const int i = idx - 16384;
        const int n = i >> 6, k = i & 63;
        WcT[i] = f2b(W_c[(k << 6) + n]);
    } else if (idx < 16384 + 4096 + 256) {
        const int i = idx - 20480;
        float v;
        if      (i < 64)  v = b_gates[64 + i];
        else if (i < 128) v = b_gates[128 + (i - 64)];
        else if (i < 192) v = b_gates[i - 128];
        else              v = b_og[i - 192];
        b2[i] = v;
    }
}

// ---------------- big GEMM: C = A(MxK) * Bt(NxK)^T + bias ----------------
// LDS rows are 32 bf16 (64B = 4x16B chunks); chunk slot ^= (row&3).
template <int BM, int BN, int WAVES_M, int WAVES_N, int A32, int C32>
__global__ __launch_bounds__(256)
void gemm_bt(const void* __restrict__ Av, const ushort* __restrict__ Bt,
             const float* __restrict__ bias, void* __restrict__ Cv,
             int M, int N, int K) {
    constexpr int WM = BM / WAVES_M, WN = BN / WAVES_N;
    constexpr int MT = WM / 16, NT = WN / 16;
    __shared__ __align__(16) ushort sA[BM * 32];
    __shared__ __align__(16) ushort sB[BN * 32];

    const int t = threadIdx.x, w = t >> 6, lane = t & 63;
    const int wm = (w / WAVES_N) * WM, wn = (w % WAVES_N) * WN;
    const long bm = (long)blockIdx.x * BM, bn = (long)blockIdx.y * BN;

    f32x4 acc[MT][NT] = {};

    for (int k0 = 0; k0 < K; k0 += 32) {
        if (A32) {
            const float* A = (const float*)Av;
            #pragma unroll
            for (int is = 0; is < BM / 32; ++is) {
                const int row = is * 32 + (t >> 3);
                const int cd = (t & 7) >> 1, half = t & 1;   // data chunk, 8B half
                const float4 v = *(const float4*)(A + (bm + row) * (long)K + k0 + (t & 7) * 4);
                *(ushort4*)&sA[row * 32 + ((cd ^ (row & 3)) * 8) + half * 4] =
                    make_ushort4(f2b(v.x), f2b(v.y), f2b(v.z), f2b(v.w));
            }
        } else {
            const ushort* A = (const ushort*)Av;
            #pragma unroll
            for (int is = 0; is < BM / 64; ++is) {
                const int row = t >> 2, kc = t & 3;
                GLOAD16(A + (bm + is * 64 + row) * (long)K + k0 + ((kc ^ (row & 3)) * 8),
                        (char*)sA + is * 4096 + w * 1024);
            }
        }
        #pragma unroll
        for (int is = 0; is < BN / 64; ++is) {
            const int row = t >> 2, kc = t & 3;
            GLOAD16(Bt + (bn + is * 64 + row) * (long)K + k0 + ((kc ^ (row & 3)) * 8),
                    (char*)sB + is * 4096 + w * 1024);
        }
        __syncthreads();

        bf16x8 af[MT], bfr[NT];
        #pragma unroll
        for (int i = 0; i < MT; ++i) {
            const int row = wm + i * 16 + (lane & 15), c = lane >> 4;
            af[i] = *(const bf16x8*)&sA[row * 32 + ((c ^ (row & 3)) * 8)];
        }
        #pragma unroll
        for (int j = 0; j < NT; ++j) {
            const int rb = wn + j * 16 + (lane & 15), c = lane >> 4;
            bfr[j] = *(const bf16x8*)&sB[rb * 32 + ((c ^ (rb & 3)) * 8)];
        }
        #pragma unroll
        for (int i = 0; i < MT; ++i)
            #pragma unroll
            for (int j = 0; j < NT; ++j)
                acc[i][j] = __builtin_amdgcn_mfma_f32_16x16x32_bf16(af[i], bfr[j], acc[i][j], 0, 0, 0);
        __syncthreads();
    }

    #pragma unroll
    for (int i = 0; i < MT; ++i)
        #pragma unroll
        for (int j = 0; j < NT; ++j) {
            const long col = bn + wn + j * 16 + (lane & 15);
            const float bv = bias[col];
            #pragma unroll
            for (int r = 0; r < 4; ++r) {
                const long row = bm + wm + i * 16 + ((lane >> 4) << 2) + r;
                const float v = acc[i][j][r] + bv;
                if (C32) ((float*)Cv)[row * (long)N + col] = v;
                else     ((ushort*)Cv)[row * (long)N + col] = f2b(v);
            }
        }
}

// ---------------- fused gate GEMM + scan ----------------
// Block = 64-row chunk. Phase1: sA(8K)+sB(32K) staging (swizzled, 128B rows).
// Phase2 aliases: sFG/sHR/sOG (64x72, conflict-free scan) + sP (64x64 swizzled).
// LDS total 48K -> 3 blocks/CU.
template <int APPLY>
__global__ __launch_bounds__(256)
void gates_scan(const ushort* __restrict__ X, const ushort* __restrict__ W2T,
                const float* __restrict__ b2, const ushort* __restrict__ WcT,
                const float* __restrict__ b_c,
                float* __restrict__ Agg, float* __restrict__ Bgg,
                const float* __restrict__ PreS, ushort* __restrict__ O) {
    __shared__ __align__(16) char smem[40960];
    ushort* sA  = (ushort*)smem;              // ph1: X 64x64 swizzled
    ushort* sB  = (ushort*)(smem + 8192);     // ph1: W2T 256x64 swizzled
    ushort* sFG = (ushort*)smem;              // ph2: 64x72
    ushort* sHR = (ushort*)(smem + 9216);
    ushort* sOG = (ushort*)(smem + 18432);
    ushort* sP  = (ushort*)(smem + 27648);    // 64x64 swizzled
    __shared__ __align__(16) ushort sWc[4096];

    const int t = threadIdx.x, w = t >> 6, lane = t & 63;
    const int blk = blockIdx.x;
    const long row0 = (long)blk * CROWS;

    {
        const int row = t >> 3, kc = t & 7;
        #pragma unroll
        for (int is = 0; is < 2; ++is)
            GLOAD16(X + (row0 + is * 32 + row) * 64 + ((kc ^ (row & 7)) * 8),
                    (char*)sA + is * 4096 + w * 1024);
        #pragma unroll
        for (int is = 0; is < 8; ++is)
            GLOAD16(W2T + (is * 32 + row) * 64 + ((kc ^ (row & 7)) * 8),
                    (char*)sB + is * 4096 + w * 1024);
        if (APPLY) {
            #pragma unroll
            for (int is = 0; is < 2; ++is)
                GLOAD16(WcT + (is * 32 + row) * 64 + ((kc ^ (row & 7)) * 8),
                        (char*)sWc + is * 4096 + w * 1024);
        }
    }
    __syncthreads();

    // gate GEMM 64x256, K=64; wave (wm, colgrp): grp0=[ig|h], grp1=[fg|og]
    const int wm = (w >> 1) * 32;
    const int grpB = w & 1;
    const int colbase = grpB * 128;
    f32x4 acc[2][8] = {};
    #pragma unroll
    for (int kk = 0; kk < 2; ++kk) {
        bf16x8 af[2];
        #pragma unroll
        for (int i = 0; i < 2; ++i) {
            const int row = wm + i * 16 + (lane & 15), c = kk * 4 + (lane >> 4);
            af[i] = *(const bf16x8*)&sA[row * 64 + ((c ^ (row & 7)) * 8)];
        }
        #pragma unroll
        for (int j = 0; j < 8; ++j) {
            const int rb = colbase + j * 16 + (lane & 15), c = kk * 4 + (lane >> 4);
            const bf16x8 bf = *(const bf16x8*)&sB[rb * 64 + ((c ^ (rb & 7)) * 8)];
            #pragma unroll
            for (int i = 0; i < 2; ++i)
                acc[i][j] = __builtin_amdgcn_mfma_f32_16x16x32_bf16(af[i], bf, acc[i][j], 0, 0, 0);
        }
    }
    __syncthreads();   // sA/sB reads complete before phase2 overwrites

    // activations: grp0 -> hr = sig(ig)*tanh(h); grp1 -> fg (and og if APPLY)
    if (!grpB) {
        #pragma unroll
        for (int jj = 0; jj < 4; ++jj) {
            const int ch = jj * 16 + (lane & 15);
            const float bi = b2[ch], bh = b2[64 + ch];
            #pragma unroll
            for (int i = 0; i < 2; ++i)
                #pragma unroll
                for (int r = 0; r < 4; ++r) {
                    const int row = wm + i * 16 + ((lane >> 4) << 2) + r;
                    const float gi = acc[i][jj][r] + bi;
                    const float gh = acc[i][jj + 4][r] + bh;
                    sHR[row * 72 + ch] = f2b(sigm(gi) * tanh_fast(gh));
                }
        }
    } else {
        #pragma unroll
        for (int jj = 0; jj < 4; ++jj) {
            const int ch = jj * 16 + (lane & 15);
            const float bfg = b2[128 + ch], bog = b2[192 + ch];
            #pragma unroll
            for (int i = 0; i < 2; ++i)
                #pragma unroll
                for (int r = 0; r < 4; ++r) {
                    const int row = wm + i * 16 + ((lane >> 4) << 2) + r;
                    sFG[row * 72 + ch] = f2b(sigm(acc[i][jj][r] + bfg));
                    if (APPLY) sOG[row * 72 + ch] = f2b(sigm(acc[i][jj + 4][r] + bog));
                }
        }
    }
    __syncthreads();

    if (!APPLY) {
        if (t < 64) {
            float a = 1.0f, b = 0.0f;
            #pragma unroll 8
            for (int r = 0; r < CROWS; ++r) {
                const float fg = b2f(sFG[r * 72 + t]);
                const float hr = b2f(sHR[r * 72 + t]);
                a *= fg;
                b = fmaf(b, fg, hr);
            }
            Agg[blk * 64 + t] = a;
            Bgg[blk * 64 + t] = b;
        }
        return;
    }

    if (t < 64) {
        float c = fmaf(PreS[(blk >> 6) * 64 + t], Agg[blk * 64 + t], Bgg[blk * 64 + t]);
        const int cch = t >> 3, half = t & 7;
        #pragma unroll 8
        for (int r = 0; r < CROWS; ++r) {
            const float fg = b2f(sFG[r * 72 + t]);
            const float hr = b2f(sHR[r * 72 + t]);
            c = fmaf(c, fg, hr);
            sP[r * 64 + ((cch ^ (r & 7)) * 8) + half] = f2b(b2f(sOG[r * 72 + t]) * c);
        }
    }
    __syncthreads();

    // O_tile = p(64x64) @ WcT^T + b_c
    const int wm2 = (w >> 1) * 32, wn2 = (w & 1) * 32;
    f32x4 acc2[2][2] = {};
    #pragma unroll
    for (int kk = 0; kk < 2; ++kk) {
        bf16x8 pa[2], wb[2];
        #pragma unroll
        for (int i = 0; i < 2; ++i) {
            const int row = wm2 + i * 16 + (lane & 15), c = kk * 4 + (lane >> 4);
            pa[i] = *(const bf16x8*)&sP[row * 64 + ((c ^ (row & 7)) * 8)];
        }
        #pragma unroll
        for (int j = 0; j < 2; ++j) {
            const int rb = wn2 + j * 16 + (lane & 15), c = kk * 4 + (lane >> 4);
            wb[j] = *(const bf16x8*)&sWc[rb * 64 + ((c ^ (rb & 7)) * 8)];
        }
        #pragma unroll
        for (int i = 0; i < 2; ++i)
            #pragma unroll
            for (int j = 0; j < 2; ++j)
                acc2[i][j] = __builtin_amdgcn_mfma_f32_16x16x32_bf16(pa[i], wb[j], acc2[i][j], 0, 0, 0);
    }
    #pragma unroll
    for (int i = 0; i < 2; ++i)
        #pragma unroll
        for (int j = 0; j < 2; ++j) {
            const int col = wn2 + j * 16 + (lane & 15);
            const float bv = b_c[col];
            #pragma unroll
            for (int r = 0; r < 4; ++r) {
                const int row = wm2 + i * 16 + ((lane >> 4) << 2) + r;
                O[(row0 + row) * 64 + col] = f2b(acc2[i][j][r] + bv);
            }
        }
}

// ---------------- two-level prefix combine ----------------
__global__ void scan_super(float* __restrict__ Agg, float* __restrict__ Bgg,
                           float* __restrict__ SA, float* __restrict__ SB) {
    const int s = blockIdx.x, ch = threadIdx.x;
    float a = 1.0f, b = 0.0f;
    #pragma unroll 8
    for (int j = 0; j < 64; ++j) {
        const int idx = (s * 64 + j) * 64 + ch;
        const float a2 = Agg[idx], bb = Bgg[idx];
        Agg[idx] = a;
        Bgg[idx] = b;
        a *= a2;
        b = fmaf(b, a2, bb);
    }
    SA[s * 64 + ch] = a;
    SB[s * 64 + ch] = b;
}

__global__ void scan_top(const float* __restrict__ SA, const float* __restrict__ SB,
                         float* __restrict__ PreS) {
    const int ch = threadIdx.x;
    float c = 0.0f;
    #pragma unroll 8
    for (int s = 0; s < 64; ++s) {
        PreS[s * 64 + ch] = c;
        c = fmaf(c, SA[s * 64 + ch], SB[s * 64 + ch]);
    }
}

// ---------------- launch ----------------
extern "C" void kernel_launch(void* const* d_in, const int* in_sizes, int n_in,
                              void* d_out, int out_size, void* d_ws, size_t ws_size,
                              hipStream_t stream) {
    const float* inputs  = (const float*)d_in[0];
    const float* W_in    = (const float*)d_in[1];
    const float* b_in    = (const float*)d_in[2];
    const float* W_gates = (const float*)d_in[3];
    const float* b_gates = (const float*)d_in[4];
    const float* W_og    = (const float*)d_in[5];
    const float* b_og    = (const float*)d_in[6];
    const float* W_c     = (const float*)d_in[7];
    const float* b_c     = (const float*)d_in[8];
    const float* W_out   = (const float*)d_in[9];
    const float* b_out   = (const float*)d_in[10];
    float* out = (float*)d_out;

    char* ws = (char*)d_ws;
    ushort* X     = (ushort*)(ws);                   // 33554432 B (O in-place)
    ushort* WinT  = (ushort*)(ws + 33554432);        // 524288
    ushort* WoutT = (ushort*)(ws + 34078720);        // 524288
    ushort* W2T   = (ushort*)(ws + 34603008);        // 32768
    ushort* WcT   = (ushort*)(ws + 34635776);        // 8192
    float*  b2    = (float*)(ws + 34643968);         // 1024
    float*  Agg   = (float*)(ws + 34644992);         // 1048576
    float*  Bgg   = (float*)(ws + 35693568);         // 1048576
    float*  SA    = (float*)(ws + 36742144);         // 16384
    float*  SB    = (float*)(ws + 36758528);         // 16384
    float*  PreS  = (float*)(ws + 36774912);         // 16384
    ushort* O = X;

    transpose512<<<dim3(16, 16), 256, 0, stream>>>(W_in, WinT);
    transpose512<<<dim3(16, 16), 256, 0, stream>>>(W_out, WoutT);
    prep_small<<<81, 256, 0, stream>>>(W_gates, W_og, W_c, b_gates, b_og, W2T, WcT, b2);

    gemm_bt<128, 128, 2, 2, 1, 0><<<dim3(256, 4), 256, 0, stream>>>(
        inputs, WinT, b_in, X, 32768, 512, 512);

    gates_scan<0><<<NCH, 256, 0, stream>>>(X, W2T, b2, WcT, b_c, Agg, Bgg, PreS, O);
    scan_super<<<NSUP, 64, 0, stream>>>(Agg, Bgg, SA, SB);
    scan_top<<<1, 64, 0, stream>>>(SA, SB, PreS);
    gates_scan<1><<<NCH, 256, 0, stream>>>(X, W2T, b2, WcT, b_c, Agg, Bgg, PreS, O);

    gemm_bt<128, 128, 2, 2, 0, 1><<<dim3(256, 4), 256, 0, stream>>>(
        O, WoutT, b_out, out, 32768, 512, 512);
}

// Round 5
// 318.339 us; speedup vs baseline: 1.1130x; 1.0197x over previous
//
#include <hip/hip_runtime.h>

// MultiHeadHPLSTM — fp32 I/O, bf16 MFMA internal.
// R4 -> R5: gates_scan restructured — register-direct MFMA fragments from
// global (no LDS staging, W2T is L2-hot), rcp-based sigmoid/tanh (no fp32
// divides), LDS 48K -> 18.4K/35.8K, launch_bounds(256,4).
// GEMM1 optionally uses a bf16 pre-convert of inputs when ws_size permits.

typedef unsigned short ushort;
typedef __bf16 bf16x8 __attribute__((ext_vector_type(8)));
typedef float f32x4 __attribute__((ext_vector_type(4)));

#define CROWS 64
#define NCH  4096
#define NSUP 64

#define GLOAD16(gp, lp) __builtin_amdgcn_global_load_lds( \
    (const __attribute__((address_space(1))) void*)(gp),  \
    (__attribute__((address_space(3))) void*)(lp), 16, 0, 0)

__device__ inline float b2f(ushort u) {
    return __builtin_bit_cast(float, (unsigned)u << 16);
}
__device__ inline ushort f2b(float f) {
    unsigned x = __builtin_bit_cast(unsigned, f);
    x += 0x7FFFu + ((x >> 16) & 1u);   // RNE
    return (ushort)(x >> 16);
}
// divide-free: v_rcp_f32 is 1-ulp, fine for bf16-rounded results
__device__ inline float sigm(float v) { return __builtin_amdgcn_rcpf(1.0f + __expf(-v)); }
__device__ inline float tanh_fast(float v) {
    return 2.0f * __builtin_amdgcn_rcpf(1.0f + __expf(-2.0f * v)) - 1.0f;
}
__device__ inline f32x4 MFMA(bf16x8 a, bf16x8 b, f32x4 c) {
    return __builtin_amdgcn_mfma_f32_16x16x32_bf16(a, b, c, 0, 0, 0);
}

// ---------------- weight prep (fp32 -> transposed bf16) ----------------
__global__ void transpose512(const float* __restrict__ src, ushort* __restrict__ dst) {
    __shared__ float tile[32][33];
    const int tx = threadIdx.x & 31, ty = threadIdx.x >> 5;
    const int x0 = blockIdx.x * 32, y0 = blockIdx.y * 32;
    #pragma unroll
    for (int dy = 0; dy < 32; dy += 8)
        tile[ty + dy][tx] = src[(size_t)(y0 + ty + dy) * 512 + x0 + tx];
    __syncthreads();
    #pragma unroll
    for (int dy = 0; dy < 32; dy += 8)
        dst[(size_t)(x0 + ty + dy) * 512 + y0 + tx] = f2b(tile[tx][ty + dy]);
}

// W2T packed col order: [ig(0..63) | h(64..127) | fg(128..191) | og(192..255)]
__global__ void prep_small(const float* __restrict__ W_gates, const float* __restrict__ W_og,
                           const float* __restrict__ W_c,
                           const float* __restrict__ b_gates, const float* __restrict__ b_og,
                           ushort* __restrict__ W2T, ushort* __restrict__ WcT, float* __restrict__ b2) {
    const int idx = blockIdx.x * 256 + threadIdx.x;
    if (idx < 16384) {
        const int n = idx >> 6, k = idx & 63;
        float v;
        if      (n < 64)  v = W_gates[k * 192 + 64 + n];          // ig
        else if (n < 128) v = W_gates[k * 192 + 128 + (n - 64)];  // h
        else if (n < 192) v = W_gates[k * 192 + (n - 128)];       // fg
        else              v = W_og[k * 64 + (n - 192)];           // og
        W2T[idx] = f2b(v);
    } else if (idx < 16384 + 4096) {
        const int i = idx - 16384;
        const int n = i >> 6, k = i & 63;
        WcT[i] = f2b(W_c[(k << 6) + n]);
    } else if (idx < 16384 + 4096 + 256) {
        const int i = idx - 20480;
        float v;
        if      (i < 64)  v = b_gates[64 + i];
        else if (i < 128) v = b_gates[128 + (i - 64)];
        else if (i < 192) v = b_gates[i - 128];
        else              v = b_og[i - 192];
        b2[i] = v;
    }
}

// fp32 -> bf16 elementwise (inputs pre-convert), 8 elems/thread
__global__ __launch_bounds__(256)
void cvt_f32_bf16(const float* __restrict__ src, ushort* __restrict__ dst) {
    const long i = ((long)blockIdx.x * 256 + threadIdx.x) * 8;
    const float4 v0 = *(const float4*)(src + i);
    const float4 v1 = *(const float4*)(src + i + 4);
    *(ushort4*)(dst + i)     = make_ushort4(f2b(v0.x), f2b(v0.y), f2b(v0.z), f2b(v0.w));
    *(ushort4*)(dst + i + 4) = make_ushort4(f2b(v1.x), f2b(v1.y), f2b(v1.z), f2b(v1.w));
}

// ---------------- big GEMM: C = A(MxK) * Bt(NxK)^T + bias ----------------
template <int BM, int BN, int WAVES_M, int WAVES_N, int A32, int C32>
__global__ __launch_bounds__(256)
void gemm_bt(const void* __restrict__ Av, const ushort* __restrict__ Bt,
             const float* __restrict__ bias, void* __restrict__ Cv,
             int M, int N, int K) {
    constexpr int WM = BM / WAVES_M, WN = BN / WAVES_N;
    constexpr int MT = WM / 16, NT = WN / 16;
    __shared__ __align__(16) ushort sA[BM * 32];
    __shared__ __align__(16) ushort sB[BN * 32];

    const int t = threadIdx.x, w = t >> 6, lane = t & 63;
    const int wm = (w / WAVES_N) * WM, wn = (w % WAVES_N) * WN;
    const long bm = (long)blockIdx.x * BM, bn = (long)blockIdx.y * BN;

    f32x4 acc[MT][NT] = {};

    for (int k0 = 0; k0 < K; k0 += 32) {
        if (A32) {
            const float* A = (const float*)Av;
            #pragma unroll
            for (int is = 0; is < BM / 32; ++is) {
                const int row = is * 32 + (t >> 3);
                const int cd = (t & 7) >> 1, half = t & 1;
                const float4 v = *(const float4*)(A + (bm + row) * (long)K + k0 + (t & 7) * 4);
                *(ushort4*)&sA[row * 32 + ((cd ^ (row & 3)) * 8) + half * 4] =
                    make_ushort4(f2b(v.x), f2b(v.y), f2b(v.z), f2b(v.w));
            }
        } else {
            const ushort* A = (const ushort*)Av;
            #pragma unroll
            for (int is = 0; is < BM / 64; ++is) {
                const int row = t >> 2, kc = t & 3;
                GLOAD16(A + (bm + is * 64 + row) * (long)K + k0 + ((kc ^ (row & 3)) * 8),
                        (char*)sA + is * 4096 + w * 1024);
            }
        }
        #pragma unroll
        for (int is = 0; is < BN / 64; ++is) {
            const int row = t >> 2, kc = t & 3;
            GLOAD16(Bt + (bn + is * 64 + row) * (long)K + k0 + ((kc ^ (row & 3)) * 8),
                    (char*)sB + is * 4096 + w * 1024);
        }
        __syncthreads();

        bf16x8 af[MT], bfr[NT];
        #pragma unroll
        for (int i = 0; i < MT; ++i) {
            const int row = wm + i * 16 + (lane & 15), c = lane >> 4;
            af[i] = *(const bf16x8*)&sA[row * 32 + ((c ^ (row & 3)) * 8)];
        }
        #pragma unroll
        for (int j = 0; j < NT; ++j) {
            const int rb = wn + j * 16 + (lane & 15), c = lane >> 4;
            bfr[j] = *(const bf16x8*)&sB[rb * 32 + ((c ^ (rb & 3)) * 8)];
        }
        #pragma unroll
        for (int i = 0; i < MT; ++i)
            #pragma unroll
            for (int j = 0; j < NT; ++j)
                acc[i][j] = MFMA(af[i], bfr[j], acc[i][j]);
        __syncthreads();
    }

    #pragma unroll
    for (int i = 0; i < MT; ++i)
        #pragma unroll
        for (int j = 0; j < NT; ++j) {
            const long col = bn + wn + j * 16 + (lane & 15);
            const float bv = bias[col];
            #pragma unroll
            for (int r = 0; r < 4; ++r) {
                const long row = bm + wm + i * 16 + ((lane >> 4) << 2) + r;
                const float v = acc[i][j][r] + bv;
                if (C32) ((float*)Cv)[row * (long)N + col] = v;
                else     ((ushort*)Cv)[row * (long)N + col] = f2b(v);
            }
        }
}

// ---------------- fused gate GEMM + scan (register-direct fragments) ----------------
// Block = 64-row chunk. No staging LDS: A/B frags via per-lane global loads
// (W2T/WcT L2-hot). LDS only for gate arrays + P tile.
template <int APPLY>
__global__ __launch_bounds__(256, 4)
void gates_scan(const ushort* __restrict__ X, const ushort* __restrict__ W2T,
                const float* __restrict__ b2, const ushort* __restrict__ WcT,
                const float* __restrict__ b_c,
                float* __restrict__ Agg, float* __restrict__ Bgg,
                const float* __restrict__ PreS, ushort* __restrict__ O) {
    __shared__ __align__(16) char smem[APPLY ? 35840 : 18432];
    ushort* sFG = (ushort*)smem;              // 64x72 (stride 72: conflict-free col reads)
    ushort* sHR = (ushort*)(smem + 9216);
    ushort* sOG = (ushort*)(smem + 18432);    // APPLY only
    ushort* sP  = (ushort*)(smem + 27648);    // 64x64 swizzled, APPLY only

    const int t = threadIdx.x, w = t >> 6, lane = t & 63;
    const int blk = blockIdx.x;
    const long row0 = (long)blk * CROWS;

    const int wm = (w >> 1) * 32;             // wave row-half
    const int grpB = w & 1;                   // 0: [ig|h]  1: [fg|og]
    const int colbase = grpB * 128;
    const int lr = lane & 15, lc = lane >> 4;

    // A fragments direct from global
    bf16x8 af[2][2];
    #pragma unroll
    for (int kk = 0; kk < 2; ++kk)
        #pragma unroll
        for (int i = 0; i < 2; ++i)
            af[kk][i] = *(const bf16x8*)(X + (row0 + wm + i * 16 + lr) * 64 + kk * 32 + lc * 8);

    // gate GEMM 32x128 per wave, K=64; B frags direct from L2
    f32x4 acc[2][8] = {};
    #pragma unroll
    for (int kk = 0; kk < 2; ++kk)
        #pragma unroll
        for (int j = 0; j < 8; ++j) {
            const bf16x8 bf = *(const bf16x8*)(W2T + (colbase + j * 16 + lr) * 64 + kk * 32 + lc * 8);
            acc[0][j] = MFMA(af[kk][0], bf, acc[0][j]);
            acc[1][j] = MFMA(af[kk][1], bf, acc[1][j]);
        }

    // activations -> LDS (bf16).  C/D layout: col = lr, row = lc*4 + r
    if (!grpB) {
        #pragma unroll
        for (int jj = 0; jj < 4; ++jj) {
            const int ch = jj * 16 + lr;
            const float bi = b2[ch], bh = b2[64 + ch];
            #pragma unroll
            for (int i = 0; i < 2; ++i)
                #pragma unroll
                for (int r = 0; r < 4; ++r) {
                    const int row = wm + i * 16 + (lc << 2) + r;
                    const float gi = acc[i][jj][r] + bi;
                    const float gh = acc[i][jj + 4][r] + bh;
                    sHR[row * 72 + ch] = f2b(sigm(gi) * tanh_fast(gh));
                }
        }
    } else {
        #pragma unroll
        for (int jj = 0; jj < 4; ++jj) {
            const int ch = jj * 16 + lr;
            const float bfg = b2[128 + ch], bog = b2[192 + ch];
            #pragma unroll
            for (int i = 0; i < 2; ++i)
                #pragma unroll
                for (int r = 0; r < 4; ++r) {
                    const int row = wm + i * 16 + (lc << 2) + r;
                    sFG[row * 72 + ch] = f2b(sigm(acc[i][jj][r] + bfg));
                    if (APPLY) sOG[row * 72 + ch] = f2b(sigm(acc[i][jj + 4][r] + bog));
                }
        }
    }
    __syncthreads();

    if (!APPLY) {
        if (t < 64) {
            float a = 1.0f, b = 0.0f;
            #pragma unroll 8
            for (int r = 0; r < CROWS; ++r) {
                const float fg = b2f(sFG[r * 72 + t]);
                const float hr = b2f(sHR[r * 72 + t]);
                a *= fg;
                b = fmaf(b, fg, hr);
            }
            Agg[blk * 64 + t] = a;
            Bgg[blk * 64 + t] = b;
        }
        return;
    }

    // APPLY: c0 from two-level prefixes, then sequential apply + p = og*c
    if (t < 64) {
        float c = fmaf(PreS[(blk >> 6) * 64 + t], Agg[blk * 64 + t], Bgg[blk * 64 + t]);
        const int cch = t >> 3, half = t & 7;
        #pragma unroll 8
        for (int r = 0; r < CROWS; ++r) {
            const float fg = b2f(sFG[r * 72 + t]);
            const float hr = b2f(sHR[r * 72 + t]);
            c = fmaf(c, fg, hr);
            sP[r * 64 + ((cch ^ (r & 7)) * 8) + half] = f2b(b2f(sOG[r * 72 + t]) * c);
        }
    }
    __syncthreads();

    // O_tile = p(64x64) @ WcT^T + b_c ; Wc frags direct from L2
    const int wn2 = grpB * 32;
    f32x4 acc2[2][2] = {};
    #pragma unroll
    for (int kk = 0; kk < 2; ++kk) {
        bf16x8 pa[2], wb[2];
        #pragma unroll
        for (int i = 0; i < 2; ++i) {
            const int row = wm + i * 16 + lr, c = kk * 4 + lc;
            pa[i] = *(const bf16x8*)&sP[row * 64 + ((c ^ (row & 7)) * 8)];
        }
        #pragma unroll
        for (int j = 0; j < 2; ++j)
            wb[j] = *(const bf16x8*)(WcT + (wn2 + j * 16 + lr) * 64 + kk * 32 + lc * 8);
        #pragma unroll
        for (int i = 0; i < 2; ++i)
            #pragma unroll
            for (int j = 0; j < 2; ++j)
                acc2[i][j] = MFMA(pa[i], wb[j], acc2[i][j]);
    }
    #pragma unroll
    for (int i = 0; i < 2; ++i)
        #pragma unroll
        for (int j = 0; j < 2; ++j) {
            const int col = wn2 + j * 16 + lr;
            const float bv = b_c[col];
            #pragma unroll
            for (int r = 0; r < 4; ++r) {
                const int row = wm + i * 16 + (lc << 2) + r;
                O[(row0 + row) * 64 + col] = f2b(acc2[i][j][r] + bv);
            }
        }
}

// ---------------- two-level prefix combine ----------------
__global__ void scan_super(float* __restrict__ Agg, float* __restrict__ Bgg,
                           float* __restrict__ SA, float* __restrict__ SB) {
    const int s = blockIdx.x, ch = threadIdx.x;
    float a = 1.0f, b = 0.0f;
    #pragma unroll 8
    for (int j = 0; j < 64; ++j) {
        const int idx = (s * 64 + j) * 64 + ch;
        const float a2 = Agg[idx], bb = Bgg[idx];
        Agg[idx] = a;
        Bgg[idx] = b;
        a *= a2;
        b = fmaf(b, a2, bb);
    }
    SA[s * 64 + ch] = a;
    SB[s * 64 + ch] = b;
}

__global__ void scan_top(const float* __restrict__ SA, const float* __restrict__ SB,
                         float* __restrict__ PreS) {
    const int ch = threadIdx.x;
    float c = 0.0f;
    #pragma unroll 8
    for (int s = 0; s < 64; ++s) {
        PreS[s * 64 + ch] = c;
        c = fmaf(c, SA[s * 64 + ch], SB[s * 64 + ch]);
    }
}

// ---------------- launch ----------------
extern "C" void kernel_launch(void* const* d_in, const int* in_sizes, int n_in,
                              void* d_out, int out_size, void* d_ws, size_t ws_size,
                              hipStream_t stream) {
    const float* inputs  = (const float*)d_in[0];
    const float* W_in    = (const float*)d_in[1];
    const float* b_in    = (const float*)d_in[2];
    const float* W_gates = (const float*)d_in[3];
    const float* b_gates = (const float*)d_in[4];
    const float* W_og    = (const float*)d_in[5];
    const float* b_og    = (const float*)d_in[6];
    const float* W_c     = (const float*)d_in[7];
    const float* b_c     = (const float*)d_in[8];
    const float* W_out   = (const float*)d_in[9];
    const float* b_out   = (const float*)d_in[10];
    float* out = (float*)d_out;

    char* ws = (char*)d_ws;
    ushort* X     = (ushort*)(ws);                   // 33554432 B (O in-place)
    ushort* WinT  = (ushort*)(ws + 33554432);        // 524288
    ushort* WoutT = (ushort*)(ws + 34078720);        // 524288
    ushort* W2T   = (ushort*)(ws + 34603008);        // 32768
    ushort* WcT   = (ushort*)(ws + 34635776);        // 8192
    float*  b2    = (float*)(ws + 34643968);         // 1024
    float*  Agg   = (float*)(ws + 34644992);         // 1048576
    float*  Bgg   = (float*)(ws + 35693568);         // 1048576
    float*  SA    = (float*)(ws + 36742144);         // 16384
    float*  SB    = (float*)(ws + 36758528);         // 16384
    float*  PreS  = (float*)(ws + 36774912);         // 16384
    ushort* Ibf   = (ushort*)(ws + 36791296);        // 33554432 (optional)
    ushort* O = X;
    const bool big_ws = ws_size >= (36791296ull + 33554432ull);   // deterministic

    transpose512<<<dim3(16, 16), 256, 0, stream>>>(W_in, WinT);
    transpose512<<<dim3(16, 16), 256, 0, stream>>>(W_out, WoutT);
    prep_small<<<81, 256, 0, stream>>>(W_gates, W_og, W_c, b_gates, b_og, W2T, WcT, b2);

    if (big_ws) {
        cvt_f32_bf16<<<8192, 256, 0, stream>>>(inputs, Ibf);
        gemm_bt<128, 128, 2, 2, 0, 0><<<dim3(256, 4), 256, 0, stream>>>(
            Ibf, WinT, b_in, X, 32768, 512, 512);
    } else {
        gemm_bt<128, 128, 2, 2, 1, 0><<<dim3(256, 4), 256, 0, stream>>>(
            inputs, WinT, b_in, X, 32768, 512, 512);
    }

    gates_scan<0><<<NCH, 256, 0, stream>>>(X, W2T, b2, WcT, b_c, Agg, Bgg, PreS, O);
    scan_super<<<NSUP, 64, 0, stream>>>(Agg, Bgg, SA, SB);
    scan_top<<<1, 64, 0, stream>>>(SA, SB, PreS);
    gates_scan<1><<<NCH, 256, 0, stream>>>(X, W2T, b2, WcT, b_c, Agg, Bgg, PreS, O);

    gemm_bt<128, 128, 2, 2, 0, 1><<<dim3(256, 4), 256, 0, stream>>>(
        O, WoutT, b_out, out, 32768, 512, 512);
}